// Round 1
// 75.792 us; speedup vs baseline: 1.0306x; 1.0306x over previous
//
#include <hip/hip_runtime.h>

#define NBINS 51
#define NT    32          // tiles per dimension (1024 / 32)
#define TILE  32          // rows per tile
#define DV4   32          // 128 floats = 32 float4 per row
#define NBLK  (NT * (NT + 1) / 2)   // 528
#define NCOPY 16
#define HSTR  103         // hist copy stride (odd -> banks decorrelated)
#define NH    (2 * NBINS) // 102: [0..50]=pos, [51..101]=neg

// ---------------------------------------------------------------------------
// Kernel 1: pairwise dots (upper triangle) + soft histogram.
// 528 blocks x 256 threads, 2x2 micro-tile per thread.
// LDS hist atomics are unsafeAtomicAdd -> native ds_add_f32 (default
// atomicAdd(float*) is a CAS loop on gfx950 and serializes under hot-bin
// contention). Epilogue: per-block partial hist written to a PRIVATE slice
// of the workspace with plain stores -- no zero-init of the buffer needed
// (kills the memset node) and no cross-block global atomic contention.
// ---------------------------------------------------------------------------
__global__ __launch_bounds__(256) void pair_hist_kernel(
    const float* __restrict__ x,
    const int*   __restrict__ labels,
    float*       __restrict__ gpart)   // [NBLK][NH]
{
    __shared__ float4 As[TILE][DV4];   // chunk c stored at c ^ ((row>>1)&7)
    __shared__ float4 Bs[TILE][DV4];
    __shared__ int    la[TILE], lb[TILE];
    __shared__ float  shist[NCOPY * HSTR];

    // Decode upper-triangular tile pair (bi <= bj).
    int rem = blockIdx.x;
    int bi = 0;
    while (rem >= NT - bi) { rem -= NT - bi; ++bi; }
    const int bj = bi + rem;

    const int t = threadIdx.x;
    for (int k = t; k < NCOPY * HSTR; k += 256) shist[k] = 0.0f;

    const float4* xv = (const float4*)x;
    #pragma unroll
    for (int k = 0; k < 4; ++k) {
        int e = t + 256 * k;
        int r = e >> 5;
        int c = e & 31;
        int sw = c ^ ((r >> 1) & 7);
        As[r][sw] = xv[(bi * TILE + r) * DV4 + c];
        Bs[r][sw] = xv[(bj * TILE + r) * DV4 + c];
    }
    if (t < TILE) {
        la[t] = labels[bi * TILE + t];
        lb[t] = labels[bj * TILE + t];
    }
    __syncthreads();

    const int tx = t & 15;
    const int ty = t >> 4;
    const int i0 = ty * 2, j0 = tx * 2;
    const int kA = ty & 7;
    const int kB = tx & 7;

    float acc00 = 0.f, acc01 = 0.f, acc10 = 0.f, acc11 = 0.f;
    #pragma unroll 4
    for (int d4 = 0; d4 < DV4; ++d4) {
        float4 a0 = As[i0    ][d4 ^ kA];
        float4 a1 = As[i0 + 1][d4 ^ kA];
        float4 b0 = Bs[j0    ][d4 ^ kB];
        float4 b1 = Bs[j0 + 1][d4 ^ kB];
        acc00 += a0.x*b0.x + a0.y*b0.y + a0.z*b0.z + a0.w*b0.w;
        acc01 += a0.x*b1.x + a0.y*b1.y + a0.z*b1.z + a0.w*b1.w;
        acc10 += a1.x*b0.x + a1.y*b0.y + a1.z*b0.z + a1.w*b0.w;
        acc11 += a1.x*b1.x + a1.y*b1.y + a1.z*b1.z + a1.w*b1.w;
    }

    const float BW = 2.0f / (NBINS - 1);
    float accs[2][2] = {{acc00, acc01}, {acc10, acc11}};
    float* myh = &shist[(t & (NCOPY - 1)) * HSTR];

    #pragma unroll
    for (int r = 0; r < 2; ++r) {
        #pragma unroll
        for (int c = 0; c < 2; ++c) {
            int gi = bi * TILE + i0 + r;
            int gj = bj * TILE + j0 + c;
            if (gi < gj) {
                float s = accs[r][c];
                int b = (int)floorf((s + 1.0f) / BW);
                b = min(max(b, 0), NBINS - 1);
                float v = (float)b * BW - 1.0f;
                float wlo = (v + BW - s) / BW;
                float whi = (s - v) / BW;
                int bh = min(b + 1, NBINS - 1);
                int base = (la[i0 + r] == lb[j0 + c]) ? 0 : NBINS;
                unsafeAtomicAdd(&myh[base + b],  wlo);   // native ds_add_f32
                unsafeAtomicAdd(&myh[base + bh], whi);
            }
        }
    }

    __syncthreads();
    // Reduce 16 copies; plain coalesced store to this block's private slice.
    if (t < NH) {
        float s = 0.f;
        #pragma unroll
        for (int c = 0; c < NCOPY; ++c) s += shist[c * HSTR + t];
        gpart[blockIdx.x * NH + t] = s;
    }
}

// ---------------------------------------------------------------------------
// Kernel 2: one block, 1024 threads. Reduces the 528 partial hists (16 waves
// of coalesced L2 reads), then one wave does sums, CDF (inclusive scan) of
// the positive hist, and the loss. sum(hist) over bins == pair count
// (w_lo + w_hi == 1 per pair), so normalizers come for free.
// ---------------------------------------------------------------------------
__global__ __launch_bounds__(1024) void finalize_kernel(
    const float* __restrict__ gpart,
    float*       __restrict__ out)
{
    __shared__ float red[10][NH];
    __shared__ float tot[NH];

    const int t = threadIdx.x;
    const int p = t / NH;          // 0..9 for t < 1020
    const int b = t - p * NH;

    if (t < 10 * NH) {
        float s = 0.f;
        #pragma unroll 4
        for (int blk = p; blk < NBLK; blk += 10)
            s += gpart[blk * NH + b];
        red[p][b] = s;
    }
    __syncthreads();

    if (t < NH) {
        float s = 0.f;
        #pragma unroll
        for (int q = 0; q < 10; ++q) s += red[q][t];
        tot[t] = s;
    }
    __syncthreads();

    if (t < 64) {
        float hp = (t < NBINS) ? tot[t]         : 0.0f;
        float hn = (t < NBINS) ? tot[NBINS + t] : 0.0f;

        float sp = hp, sn = hn;
        #pragma unroll
        for (int off = 32; off > 0; off >>= 1) {
            sp += __shfl_xor(sp, off, 64);
            sn += __shfl_xor(sn, off, 64);
        }

        float cdf = hp;
        #pragma unroll
        for (int off = 1; off < 64; off <<= 1) {
            float v = __shfl_up(cdf, off, 64);
            if (t >= off) cdf += v;
        }

        float contrib = hn * cdf;
        #pragma unroll
        for (int off = 32; off > 0; off >>= 1)
            contrib += __shfl_xor(contrib, off, 64);

        if (t == 0) out[0] = contrib / (sp * sn);
    }
}

extern "C" void kernel_launch(void* const* d_in, const int* in_sizes, int n_in,
                              void* d_out, int out_size, void* d_ws, size_t ws_size,
                              hipStream_t stream)
{
    const float* x      = (const float*)d_in[0];
    const int*   labels = (const int*)d_in[1];
    float*       gpart  = (float*)d_ws;     // [NBLK][NH] partial hists

    pair_hist_kernel<<<NBLK, 256, 0, stream>>>(x, labels, gpart);
    finalize_kernel<<<1, 1024, 0, stream>>>(gpart, (float*)d_out);
}

// Round 2
// 72.550 us; speedup vs baseline: 1.0766x; 1.0447x over previous
//
#include <hip/hip_runtime.h>

#define NBINS 51
#define NT    32          // tiles per dimension (1024 / 32)
#define TILE  32          // rows per tile
#define DV4   32          // 128 floats = 32 float4 per row
#define NBLK  (NT * (NT + 1) / 2)   // 528
#define NCOPY 16
#define HSTR  103         // hist copy stride (odd -> banks decorrelated)
#define NH    (2 * NBINS) // 102: [0..50]=pos, [51..101]=neg
#define PSTR  128         // padded partial-hist stride (512 B, float4 aligned)

// ---------------------------------------------------------------------------
// Kernel 1: pairwise dots (upper triangle) + soft histogram.
// 528 blocks x 256 threads, 2x2 micro-tile per thread.
// LDS hist atomics are unsafeAtomicAdd -> native ds_add_f32 (default
// atomicAdd(float*) is a CAS loop on gfx950 and serializes under hot-bin
// contention). Epilogue: per-block partial hist (padded to 128 floats so
// finalize can read float4) written to a PRIVATE workspace slice with plain
// stores -- no zero-init needed, no cross-block atomic contention.
// ---------------------------------------------------------------------------
__global__ __launch_bounds__(256) void pair_hist_kernel(
    const float* __restrict__ x,
    const int*   __restrict__ labels,
    float*       __restrict__ gpart)   // [NBLK][PSTR]
{
    __shared__ float4 As[TILE][DV4];   // chunk c stored at c ^ ((row>>1)&7)
    __shared__ float4 Bs[TILE][DV4];
    __shared__ int    la[TILE], lb[TILE];
    __shared__ float  shist[NCOPY * HSTR];

    // Decode upper-triangular tile pair (bi <= bj).
    int rem = blockIdx.x;
    int bi = 0;
    while (rem >= NT - bi) { rem -= NT - bi; ++bi; }
    const int bj = bi + rem;

    const int t = threadIdx.x;
    for (int k = t; k < NCOPY * HSTR; k += 256) shist[k] = 0.0f;

    const float4* xv = (const float4*)x;
    #pragma unroll
    for (int k = 0; k < 4; ++k) {
        int e = t + 256 * k;
        int r = e >> 5;
        int c = e & 31;
        int sw = c ^ ((r >> 1) & 7);
        As[r][sw] = xv[(bi * TILE + r) * DV4 + c];
        Bs[r][sw] = xv[(bj * TILE + r) * DV4 + c];
    }
    if (t < TILE) {
        la[t] = labels[bi * TILE + t];
        lb[t] = labels[bj * TILE + t];
    }
    __syncthreads();

    const int tx = t & 15;
    const int ty = t >> 4;
    const int i0 = ty * 2, j0 = tx * 2;
    const int kA = ty & 7;
    const int kB = tx & 7;

    float acc00 = 0.f, acc01 = 0.f, acc10 = 0.f, acc11 = 0.f;
    #pragma unroll 4
    for (int d4 = 0; d4 < DV4; ++d4) {
        float4 a0 = As[i0    ][d4 ^ kA];
        float4 a1 = As[i0 + 1][d4 ^ kA];
        float4 b0 = Bs[j0    ][d4 ^ kB];
        float4 b1 = Bs[j0 + 1][d4 ^ kB];
        acc00 += a0.x*b0.x + a0.y*b0.y + a0.z*b0.z + a0.w*b0.w;
        acc01 += a0.x*b1.x + a0.y*b1.y + a0.z*b1.z + a0.w*b1.w;
        acc10 += a1.x*b0.x + a1.y*b0.y + a1.z*b0.z + a1.w*b0.w;
        acc11 += a1.x*b1.x + a1.y*b1.y + a1.z*b1.z + a1.w*b1.w;
    }

    const float BW = 2.0f / (NBINS - 1);
    float accs[2][2] = {{acc00, acc01}, {acc10, acc11}};
    float* myh = &shist[(t & (NCOPY - 1)) * HSTR];

    #pragma unroll
    for (int r = 0; r < 2; ++r) {
        #pragma unroll
        for (int c = 0; c < 2; ++c) {
            int gi = bi * TILE + i0 + r;
            int gj = bj * TILE + j0 + c;
            if (gi < gj) {
                float s = accs[r][c];
                int b = (int)floorf((s + 1.0f) / BW);
                b = min(max(b, 0), NBINS - 1);
                float v = (float)b * BW - 1.0f;
                float wlo = (v + BW - s) / BW;
                float whi = (s - v) / BW;
                int bh = min(b + 1, NBINS - 1);
                int base = (la[i0 + r] == lb[j0 + c]) ? 0 : NBINS;
                unsafeAtomicAdd(&myh[base + b],  wlo);   // native ds_add_f32
                unsafeAtomicAdd(&myh[base + bh], whi);
            }
        }
    }

    __syncthreads();
    // Reduce 16 copies; plain coalesced 512 B store to this block's slice.
    if (t < PSTR) {
        float s = 0.f;
        if (t < NH) {
            #pragma unroll
            for (int c = 0; c < NCOPY; ++c) s += shist[c * HSTR + t];
        }
        gpart[blockIdx.x * PSTR + t] = s;   // pad lanes store 0
    }
}

// ---------------------------------------------------------------------------
// Kernel 2: one block, 1024 threads. Each thread owns one float4 column of
// the [528][32] float4 partial matrix and sums 16-17 fully-unrolled
// INDEPENDENT loads (deep MLP: ~16 KB in flight per wave -> the whole 270 KB
// read is one latency window instead of a dependent-chain crawl). Then a
// 32-way LDS reduction, then one wave does sums, CDF scan, and the loss.
// sum(hist) over bins == pair count, so normalizers come for free.
// ---------------------------------------------------------------------------
__global__ __launch_bounds__(1024) void finalize_kernel(
    const float* __restrict__ gpart,
    float*       __restrict__ out)
{
    __shared__ float red[32][PSTR];
    __shared__ float tot[PSTR];

    const int t = threadIdx.x;
    const int p = t >> 5;          // block-group 0..31
    const int c = t & 31;          // float4 column 0..31

    const float4* g4 = (const float4*)gpart;   // row stride = 32 float4

    float4 acc = make_float4(0.f, 0.f, 0.f, 0.f);
    #pragma unroll
    for (int k = 0; k < 16; ++k) {             // blocks p, p+32, ..., p+480
        float4 v = g4[(p + (k << 5)) * 32 + c];
        acc.x += v.x; acc.y += v.y; acc.z += v.z; acc.w += v.w;
    }
    if (p < 16) {                              // tail blocks 512..527
        float4 v = g4[(p + 512) * 32 + c];
        acc.x += v.x; acc.y += v.y; acc.z += v.z; acc.w += v.w;
    }
    *(float4*)&red[p][c * 4] = acc;
    __syncthreads();

    if (t < PSTR) {
        float s = 0.f;
        #pragma unroll
        for (int q = 0; q < 32; ++q) s += red[q][t];
        tot[t] = s;
    }
    __syncthreads();

    if (t < 64) {
        float hp = (t < NBINS) ? tot[t]         : 0.0f;
        float hn = (t < NBINS) ? tot[NBINS + t] : 0.0f;

        float sp = hp, sn = hn;
        #pragma unroll
        for (int off = 32; off > 0; off >>= 1) {
            sp += __shfl_xor(sp, off, 64);
            sn += __shfl_xor(sn, off, 64);
        }

        float cdf = hp;
        #pragma unroll
        for (int off = 1; off < 64; off <<= 1) {
            float v = __shfl_up(cdf, off, 64);
            if (t >= off) cdf += v;
        }

        float contrib = hn * cdf;
        #pragma unroll
        for (int off = 32; off > 0; off >>= 1)
            contrib += __shfl_xor(contrib, off, 64);

        if (t == 0) out[0] = contrib / (sp * sn);
    }
}

extern "C" void kernel_launch(void* const* d_in, const int* in_sizes, int n_in,
                              void* d_out, int out_size, void* d_ws, size_t ws_size,
                              hipStream_t stream)
{
    const float* x      = (const float*)d_in[0];
    const int*   labels = (const int*)d_in[1];
    float*       gpart  = (float*)d_ws;     // [NBLK][PSTR] partial hists

    pair_hist_kernel<<<NBLK, 256, 0, stream>>>(x, labels, gpart);
    finalize_kernel<<<1, 1024, 0, stream>>>(gpart, (float*)d_out);
}